// Round 8
// baseline (331.551 us; speedup 1.0000x reference)
//
#include <hip/hip_runtime.h>
#include <hip/hip_cooperative_groups.h>

namespace cg = cooperative_groups;

#define NEG_SLOPE 0.2f
#define EPSV 1e-16f
#define NHEADS 8
#define NCH 16
#define BKT_SHIFT 8        // 256 nodes per bucket
#define BKT_NODES 256
#define CAP 8192           // fixed bucket capacity (mean 4096 for E=1.6M)
#define BIN_EPB 4096       // edges per block in bin phase (16/thread)
#define MAX_BKT 512

// One cooperative kernel, 3 phases separated by grid.sync():
//  A: bin edges into per-bucket regions (block-aggregated reservations)
//  B: per-bucket LDS counting sort + layer-1 per-node register gather -> h2
//  C: layer-2 gather reusing the sorted src lists STILL IN LDS
__global__ __launch_bounds__(256, 2) void gat_fused_kernel(
        int N, int E, int nbuckets,
        const float* __restrict__ x, const int* __restrict__ ei,
        const float* __restrict__ W1, const float* __restrict__ as1,
        const float* __restrict__ ad1, const float* __restrict__ b1,
        const float* __restrict__ W2, const float* __restrict__ as2,
        const float* __restrict__ ad2, const float* __restrict__ b2,
        int* __restrict__ bkt_cnt, unsigned int* __restrict__ binned,
        float* __restrict__ h2, float* __restrict__ out) {
    cg::grid_group grid = cg::this_grid();
    __shared__ unsigned int ed[CAP];          // 32 KB; aliased by hist/gbase in A
    __shared__ int cnt[BKT_NODES];
    __shared__ int cur[BKT_NODES];
    __shared__ int offs[BKT_NODES];
    __shared__ float xloc[BKT_NODES];
    __shared__ float sS1[NHEADS], sD1[NHEADS];

    int b = blockIdx.x, t = threadIdx.x;

    // Attention scalars (once per block; W1/att tiny + L2-hot).
    if (t < NHEADS) {
        float s = 0.f, d = 0.f;
        for (int c = 0; c < NCH; ++c) {
            float w = W1[t * NCH + c];
            s += w * as1[t * NCH + c];
            d += w * ad1[t * NCH + c];
        }
        sS1[t] = s; sD1[t] = d;
    }

    // ---------------- Phase A: bin ----------------
    int* hist  = (int*)&ed[0];        // [MAX_BKT] alias (ed dead in phase A)
    int* gbase = hist + MAX_BKT;      // [MAX_BKT]
    for (int i = t; i < nbuckets; i += 256) hist[i] = 0;
    __syncthreads();
    int base = b * BIN_EPB;
    int lr[BIN_EPB / 256];            // 16 local ranks
#pragma unroll
    for (int k = 0; k < BIN_EPB / 1024; ++k) {
        int idx = base + k * 1024 + t * 4;
        if (idx + 3 < E) {
            int4 d4 = *(const int4*)(ei + E + idx);
            lr[4 * k + 0] = atomicAdd(&hist[d4.x >> BKT_SHIFT], 1);
            lr[4 * k + 1] = atomicAdd(&hist[d4.y >> BKT_SHIFT], 1);
            lr[4 * k + 2] = atomicAdd(&hist[d4.z >> BKT_SHIFT], 1);
            lr[4 * k + 3] = atomicAdd(&hist[d4.w >> BKT_SHIFT], 1);
        } else {
            for (int u = 0; u < 4; ++u)
                if (idx + u < E)
                    lr[4 * k + u] = atomicAdd(&hist[ei[E + idx + u] >> BKT_SHIFT], 1);
        }
    }
    __syncthreads();
    for (int i = t; i < nbuckets; i += 256) {
        int c = hist[i];
        gbase[i] = c ? (i * CAP + atomicAdd(&bkt_cnt[i], c)) : 0;
    }
    __syncthreads();
#pragma unroll
    for (int k = 0; k < BIN_EPB / 1024; ++k) {
        int idx = base + k * 1024 + t * 4;
        if (idx + 3 < E) {
            int4 s4 = *(const int4*)(ei + idx);
            int4 d4 = *(const int4*)(ei + E + idx);
            binned[gbase[d4.x >> BKT_SHIFT] + lr[4 * k + 0]] =
                ((unsigned int)s4.x << BKT_SHIFT) | (unsigned int)(d4.x & (BKT_NODES - 1));
            binned[gbase[d4.y >> BKT_SHIFT] + lr[4 * k + 1]] =
                ((unsigned int)s4.y << BKT_SHIFT) | (unsigned int)(d4.y & (BKT_NODES - 1));
            binned[gbase[d4.z >> BKT_SHIFT] + lr[4 * k + 2]] =
                ((unsigned int)s4.z << BKT_SHIFT) | (unsigned int)(d4.z & (BKT_NODES - 1));
            binned[gbase[d4.w >> BKT_SHIFT] + lr[4 * k + 3]] =
                ((unsigned int)s4.w << BKT_SHIFT) | (unsigned int)(d4.w & (BKT_NODES - 1));
        } else {
            for (int u = 0; u < 4; ++u)
                if (idx + u < E) {
                    unsigned int s = (unsigned int)ei[idx + u];
                    int d = ei[E + idx + u];
                    binned[gbase[d >> BKT_SHIFT] + lr[4 * k + u]] =
                        (s << BKT_SHIFT) | (unsigned int)(d & (BKT_NODES - 1));
                }
        }
    }
    __threadfence();
    grid.sync();

    // ------------- Phase B: sort + layer-1 gather -------------
    int node = (b << BKT_SHIFT) + t;
    float xn = (node < N) ? x[node] : 0.f;
    xloc[t] = xn;
    cnt[t] = 0;
    __syncthreads();
    int nE = (b < nbuckets) ? bkt_cnt[b] : 0;
    if (nE > CAP) nE = CAP;
    const unsigned int* bb = binned + (size_t)b * CAP;
    // count local dsts
    for (int j0 = 0; j0 < nE; j0 += 1024) {
        int idx = j0 + t * 4;
        if (idx + 3 < nE) {
            uint4 q = *(const uint4*)(bb + idx);
            atomicAdd(&cnt[q.x & (BKT_NODES - 1)], 1);
            atomicAdd(&cnt[q.y & (BKT_NODES - 1)], 1);
            atomicAdd(&cnt[q.z & (BKT_NODES - 1)], 1);
            atomicAdd(&cnt[q.w & (BKT_NODES - 1)], 1);
        } else {
            for (int u = 0; u < 4; ++u)
                if (idx + u < nE) atomicAdd(&cnt[bb[idx + u] & (BKT_NODES - 1)], 1);
        }
    }
    __syncthreads();
    // 256-wide Hillis-Steele exclusive scan
    int c = cnt[t];
    offs[t] = c;
    __syncthreads();
    for (int o = 1; o < 256; o <<= 1) {
        int v = (t >= o) ? offs[t - o] : 0;
        __syncthreads();
        offs[t] += v;
        __syncthreads();
    }
    int o_excl = offs[t] - c;
    cur[t] = o_excl;
    __syncthreads();
    // scatter src ids into sorted LDS positions
    for (int j0 = 0; j0 < nE; j0 += 1024) {
        int idx = j0 + t * 4;
        if (idx + 3 < nE) {
            uint4 q = *(const uint4*)(bb + idx);
            ed[atomicAdd(&cur[q.x & (BKT_NODES - 1)], 1)] = q.x >> BKT_SHIFT;
            ed[atomicAdd(&cur[q.y & (BKT_NODES - 1)], 1)] = q.y >> BKT_SHIFT;
            ed[atomicAdd(&cur[q.z & (BKT_NODES - 1)], 1)] = q.z >> BKT_SHIFT;
            ed[atomicAdd(&cur[q.w & (BKT_NODES - 1)], 1)] = q.w >> BKT_SHIFT;
        } else {
            for (int u = 0; u < 4; ++u)
                if (idx + u < nE) {
                    unsigned int v = bb[idx + u];
                    ed[atomicAdd(&cur[v & (BKT_NODES - 1)], 1)] = v >> BKT_SHIFT;
                }
        }
    }
    __syncthreads();
    // per-node register gather (no atomics), unroll-4 for load MLP
    float S1[NHEADS], A[NHEADS], den[NHEADS], num[NHEADS];
#pragma unroll
    for (int h = 0; h < NHEADS; ++h) {
        S1[h] = sS1[h];
        A[h] = xn * sD1[h];
        float e = xn * S1[h] + A[h];          // self-loop
        e = e > 0.f ? e : NEG_SLOPE * e;
        float ex = __expf(e);
        den[h] = ex + EPSV;
        num[h] = ex * xn;
    }
    int j = 0;
    for (; j + 4 <= c; j += 4) {
        unsigned int e0 = ed[o_excl + j + 0], e1 = ed[o_excl + j + 1];
        unsigned int e2 = ed[o_excl + j + 2], e3 = ed[o_excl + j + 3];
        float x0 = x[e0], x1 = x[e1], x2 = x[e2], x3 = x[e3];
#pragma unroll
        for (int h = 0; h < NHEADS; ++h) {
            float ea = x0 * S1[h] + A[h]; ea = ea > 0.f ? ea : NEG_SLOPE * ea;
            float eb = x1 * S1[h] + A[h]; eb = eb > 0.f ? eb : NEG_SLOPE * eb;
            float ec = x2 * S1[h] + A[h]; ec = ec > 0.f ? ec : NEG_SLOPE * ec;
            float ee = x3 * S1[h] + A[h]; ee = ee > 0.f ? ee : NEG_SLOPE * ee;
            float fa = __expf(ea), fb = __expf(eb), fc = __expf(ec), fd = __expf(ee);
            den[h] += (fa + fb) + (fc + fd);
            num[h] += (fa * x0 + fb * x1) + (fc * x2 + fd * x3);
        }
    }
    for (; j < c; ++j) {
        unsigned int e0 = ed[o_excl + j];
        float x0 = x[e0];
#pragma unroll
        for (int h = 0; h < NHEADS; ++h) {
            float ea = x0 * S1[h] + A[h];
            ea = ea > 0.f ? ea : NEG_SLOPE * ea;
            float fa = __expf(ea);
            den[h] += fa;
            num[h] += fa * x0;
        }
    }
    float h2val = 0.f;
#pragma unroll
    for (int h = 0; h < NHEADS; ++h) {
        float z = num[h] / den[h];
#pragma unroll
        for (int ccc = 0; ccc < NCH; ++ccc) {
            int k = h * NCH + ccc;
            float vv = W1[k] * z + b1[k];
            vv = vv > 0.f ? vv : (__expf(vv) - 1.f);   // elu
            h2val += vv * W2[k];
        }
    }
    if (node < N) h2[node] = h2val;
    __threadfence();
    grid.sync();

    // ------------- Phase C: layer-2 gather (ed still in LDS) -------------
    float a_s = as2[0], a_d = ad2[0];
    float hn = h2val;
    float adc = hn * a_d;
    float e2s = hn * (a_s + a_d);             // self-loop
    e2s = e2s > 0.f ? e2s : NEG_SLOPE * e2s;
    float ex2 = __expf(e2s);
    float den2 = ex2 + EPSV;
    float num2 = ex2 * hn;
    j = 0;
    for (; j + 4 <= c; j += 4) {
        unsigned int e0 = ed[o_excl + j + 0], e1 = ed[o_excl + j + 1];
        unsigned int e2 = ed[o_excl + j + 2], e3 = ed[o_excl + j + 3];
        float h0 = h2[e0], h1 = h2[e1], h3 = h2[e2], h4 = h2[e3];
        float ea = h0 * a_s + adc; ea = ea > 0.f ? ea : NEG_SLOPE * ea;
        float eb = h1 * a_s + adc; eb = eb > 0.f ? eb : NEG_SLOPE * eb;
        float ec = h3 * a_s + adc; ec = ec > 0.f ? ec : NEG_SLOPE * ec;
        float ee = h4 * a_s + adc; ee = ee > 0.f ? ee : NEG_SLOPE * ee;
        float fa = __expf(ea), fb = __expf(eb), fc = __expf(ec), fd = __expf(ee);
        den2 += (fa + fb) + (fc + fd);
        num2 += (fa * h0 + fb * h1) + (fc * h3 + fd * h4);
    }
    for (; j < c; ++j) {
        unsigned int e0 = ed[o_excl + j];
        float h0 = h2[e0];
        float ea = h0 * a_s + adc;
        ea = ea > 0.f ? ea : NEG_SLOPE * ea;
        float fa = __expf(ea);
        den2 += fa;
        num2 += fa * h0;
    }
    if (node < N) out[node] = num2 / den2 + b2[0];
}

extern "C" void kernel_launch(void* const* d_in, const int* in_sizes, int n_in,
                              void* d_out, int out_size, void* d_ws, size_t ws_size,
                              hipStream_t stream) {
    const float* x   = (const float*)d_in[0];
    const int*   ei  = (const int*)d_in[1];
    const float* W1  = (const float*)d_in[2];
    const float* as1 = (const float*)d_in[3];
    const float* ad1 = (const float*)d_in[4];
    const float* b1  = (const float*)d_in[5];
    const float* W2  = (const float*)d_in[6];
    const float* as2 = (const float*)d_in[7];
    const float* ad2 = (const float*)d_in[8];
    const float* b2  = (const float*)d_in[9];
    float* out = (float*)d_out;

    int N = in_sizes[0];       // 100000
    int E = in_sizes[1] / 2;   // 1600000

    int nbuckets = (N + BKT_NODES - 1) >> BKT_SHIFT;   // 391
    int nbin     = (E + BIN_EPB - 1) / BIN_EPB;        // 391
    int nblocks  = nbuckets > nbin ? nbuckets : nbin;  // 391

    // Workspace: h2[N]f | bkt_cnt[nbuckets]i | binned[nbuckets*CAP]u
    float* h2      = (float*)d_ws;
    int*   bkt_cnt = (int*)(h2 + N);
    unsigned int* binned = (unsigned int*)(bkt_cnt + nbuckets);

    hipMemsetAsync(bkt_cnt, 0, (size_t)nbuckets * sizeof(int), stream);

    void* args[] = {
        &N, &E, &nbuckets, &x, &ei, &W1, &as1, &ad1, &b1, &W2,
        &as2, &ad2, &b2, &bkt_cnt, &binned, &h2, &out
    };
    hipLaunchCooperativeKernel((void*)gat_fused_kernel, dim3(nblocks), dim3(256),
                               args, 0, stream);
}

// Round 9
// 166.020 us; speedup vs baseline: 1.9971x; 1.9971x over previous
//
#include <hip/hip_runtime.h>

#define NEG_SLOPE 0.2f
#define EPSV 1e-16f
#define NHEADS 8
#define NCH 16
#define BKT_SHIFT 6        // 64 nodes per bucket
#define BKT_NODES 64
#define CAP 2048           // bucket capacity (mean 1024, +32 sigma)
#define BIN_EPB 8192       // edges per block in bin pass (32/thread)
#define NBKT_MAX 1600

// Bin pass, block-aggregated: LDS bucket histogram gives local ranks; one
// global atomic per (block, nonempty bucket) reserves a contiguous range at
// fixed offset b*CAP; clustered writes of packed (src<<6 | dst&63).
__global__ __launch_bounds__(256) void gat_bin_kernel(
        const int* __restrict__ ei, int E, int nbuckets,
        int* __restrict__ bkt_cnt, unsigned int* __restrict__ binned) {
    __shared__ int hist[NBKT_MAX];
    __shared__ int gbase[NBKT_MAX];
    int t = threadIdx.x;
    for (int i = t; i < nbuckets; i += 256) hist[i] = 0;
    __syncthreads();
    int base = blockIdx.x * BIN_EPB;
    int lr[BIN_EPB / 256];   // 32 local ranks
#pragma unroll
    for (int k = 0; k < BIN_EPB / 1024; ++k) {
        int idx = base + k * 1024 + t * 4;
        if (idx + 3 < E) {
            int4 d4 = *(const int4*)(ei + E + idx);
            lr[4 * k + 0] = atomicAdd(&hist[d4.x >> BKT_SHIFT], 1);
            lr[4 * k + 1] = atomicAdd(&hist[d4.y >> BKT_SHIFT], 1);
            lr[4 * k + 2] = atomicAdd(&hist[d4.z >> BKT_SHIFT], 1);
            lr[4 * k + 3] = atomicAdd(&hist[d4.w >> BKT_SHIFT], 1);
        } else {
            for (int u = 0; u < 4; ++u)
                if (idx + u < E)
                    lr[4 * k + u] = atomicAdd(&hist[ei[E + idx + u] >> BKT_SHIFT], 1);
        }
    }
    __syncthreads();
    for (int i = t; i < nbuckets; i += 256) {
        int c = hist[i];
        gbase[i] = c ? (i * CAP + atomicAdd(&bkt_cnt[i], c)) : 0;
    }
    __syncthreads();
#pragma unroll
    for (int k = 0; k < BIN_EPB / 1024; ++k) {
        int idx = base + k * 1024 + t * 4;
        if (idx + 3 < E) {
            int4 s4 = *(const int4*)(ei + idx);
            int4 d4 = *(const int4*)(ei + E + idx);
            binned[gbase[d4.x >> BKT_SHIFT] + lr[4 * k + 0]] =
                ((unsigned int)s4.x << BKT_SHIFT) | (unsigned int)(d4.x & (BKT_NODES - 1));
            binned[gbase[d4.y >> BKT_SHIFT] + lr[4 * k + 1]] =
                ((unsigned int)s4.y << BKT_SHIFT) | (unsigned int)(d4.y & (BKT_NODES - 1));
            binned[gbase[d4.z >> BKT_SHIFT] + lr[4 * k + 2]] =
                ((unsigned int)s4.z << BKT_SHIFT) | (unsigned int)(d4.z & (BKT_NODES - 1));
            binned[gbase[d4.w >> BKT_SHIFT] + lr[4 * k + 3]] =
                ((unsigned int)s4.w << BKT_SHIFT) | (unsigned int)(d4.w & (BKT_NODES - 1));
        } else {
            for (int u = 0; u < 4; ++u)
                if (idx + u < E) {
                    unsigned int s = (unsigned int)ei[idx + u];
                    int d = ei[E + idx + u];
                    binned[gbase[d >> BKT_SHIFT] + lr[4 * k + u]] =
                        (s << BKT_SHIFT) | (unsigned int)(d & (BKT_NODES - 1));
                }
        }
    }
}

// Layer 1: one block per 64-node bucket, 4 threads per node.
// LDS counting sort, then per-node register gather split 4 ways; partials
// combined via 16 LDS atomics/thread. Writes sorted srcs + row meta + h2.
__global__ __launch_bounds__(256) void gat_gather1_kernel(
        int N, const float* __restrict__ x,
        unsigned int* __restrict__ binned, const int* __restrict__ bkt_cnt,
        const float* __restrict__ W1, const float* __restrict__ as1,
        const float* __restrict__ ad1, const float* __restrict__ b1,
        const float* __restrict__ W2, float* __restrict__ h2out,
        int* __restrict__ row_start, int* __restrict__ row_deg) {
    __shared__ unsigned int ed[CAP];          // 8 KB sorted srcs
    __shared__ int cnt[BKT_NODES], offs[BKT_NODES], cur[BKT_NODES];
    __shared__ float xloc[BKT_NODES];
    __shared__ float sS1[NHEADS], sD1[NHEADS];
    __shared__ float accD[NHEADS][BKT_NODES]; // 2 KB
    __shared__ float accN[NHEADS][BKT_NODES]; // 2 KB
    int b = blockIdx.x, t = threadIdx.x;
    int loc = t & (BKT_NODES - 1);
    int q = t >> BKT_SHIFT;                   // 0..3
    if (t < NHEADS) {
        float s = 0.f, d = 0.f;
        for (int c = 0; c < NCH; ++c) {
            float w = W1[t * NCH + c];
            s += w * as1[t * NCH + c];
            d += w * ad1[t * NCH + c];
        }
        sS1[t] = s; sD1[t] = d;
    }
    if (t < BKT_NODES) {
        int node = (b << BKT_SHIFT) + t;
        xloc[t] = (node < N) ? x[node] : 0.f;
        cnt[t] = 0;
    }
    for (int i = t; i < NHEADS * BKT_NODES; i += 256) {
        (&accD[0][0])[i] = 0.f;
        (&accN[0][0])[i] = 0.f;
    }
    __syncthreads();
    int nE = bkt_cnt[b]; if (nE > CAP) nE = CAP;
    const unsigned int* bb = binned + (size_t)b * CAP;
    // count local dsts
    for (int j0 = 0; j0 < nE; j0 += 1024) {
        int idx = j0 + t * 4;
        if (idx + 3 < nE) {
            uint4 qv = *(const uint4*)(bb + idx);
            atomicAdd(&cnt[qv.x & (BKT_NODES - 1)], 1);
            atomicAdd(&cnt[qv.y & (BKT_NODES - 1)], 1);
            atomicAdd(&cnt[qv.z & (BKT_NODES - 1)], 1);
            atomicAdd(&cnt[qv.w & (BKT_NODES - 1)], 1);
        } else {
            for (int u = 0; u < 4; ++u)
                if (idx + u < nE) atomicAdd(&cnt[bb[idx + u] & (BKT_NODES - 1)], 1);
        }
    }
    __syncthreads();
    // 64-wide Hillis-Steele inclusive scan in LDS
    if (t < BKT_NODES) offs[t] = cnt[t];
    __syncthreads();
    for (int o = 1; o < BKT_NODES; o <<= 1) {
        int v = (t < BKT_NODES && t >= o) ? offs[t - o] : 0;
        __syncthreads();
        if (t < BKT_NODES) offs[t] += v;
        __syncthreads();
    }
    if (t < BKT_NODES) cur[t] = offs[t] - cnt[t];
    __syncthreads();
    // scatter srcs into sorted LDS positions
    for (int j0 = 0; j0 < nE; j0 += 1024) {
        int idx = j0 + t * 4;
        if (idx + 3 < nE) {
            uint4 qv = *(const uint4*)(bb + idx);
            ed[atomicAdd(&cur[qv.x & (BKT_NODES - 1)], 1)] = qv.x >> BKT_SHIFT;
            ed[atomicAdd(&cur[qv.y & (BKT_NODES - 1)], 1)] = qv.y >> BKT_SHIFT;
            ed[atomicAdd(&cur[qv.z & (BKT_NODES - 1)], 1)] = qv.z >> BKT_SHIFT;
            ed[atomicAdd(&cur[qv.w & (BKT_NODES - 1)], 1)] = qv.w >> BKT_SHIFT;
        } else {
            for (int u = 0; u < 4; ++u)
                if (idx + u < nE) {
                    unsigned int v = bb[idx + u];
                    ed[atomicAdd(&cur[v & (BKT_NODES - 1)], 1)] = v >> BKT_SHIFT;
                }
        }
    }
    __syncthreads();
    // write back sorted srcs for layer 2 (coalesced)
    for (int j0 = 0; j0 < nE; j0 += 1024) {
        int idx = j0 + t * 4;
        if (idx + 3 < nE) {
            *(uint4*)(binned + (size_t)b * CAP + idx) = *(const uint4*)(ed + idx);
        } else {
            for (int u = 0; u < 4; ++u)
                if (idx + u < nE) binned[(size_t)b * CAP + idx + u] = ed[idx + u];
        }
    }
    // per-node gather split across 4 threads
    int deg = cnt[loc];
    int ob = offs[loc] - deg;
    int lo = ob + (deg * q) / 4;
    int hi = ob + (deg * (q + 1)) / 4;
    float xd = xloc[loc];
    float S1[NHEADS], A[NHEADS], den[NHEADS], num[NHEADS];
#pragma unroll
    for (int h = 0; h < NHEADS; ++h) {
        S1[h] = sS1[h];
        A[h] = xd * sD1[h];
        den[h] = 0.f;
        num[h] = 0.f;
    }
    int j = lo;
    for (; j + 2 <= hi; j += 2) {
        unsigned int e0 = ed[j], e1 = ed[j + 1];
        float x0 = x[e0], x1 = x[e1];
#pragma unroll
        for (int h = 0; h < NHEADS; ++h) {
            float ea = x0 * S1[h] + A[h]; ea = ea > 0.f ? ea : NEG_SLOPE * ea;
            float eb = x1 * S1[h] + A[h]; eb = eb > 0.f ? eb : NEG_SLOPE * eb;
            float fa = __expf(ea), fb = __expf(eb);
            den[h] += fa + fb;
            num[h] += fa * x0 + fb * x1;
        }
    }
    if (j < hi) {
        unsigned int e0 = ed[j];
        float x0 = x[e0];
#pragma unroll
        for (int h = 0; h < NHEADS; ++h) {
            float ea = x0 * S1[h] + A[h];
            ea = ea > 0.f ? ea : NEG_SLOPE * ea;
            float fa = __expf(ea);
            den[h] += fa;
            num[h] += fa * x0;
        }
    }
#pragma unroll
    for (int h = 0; h < NHEADS; ++h) {
        atomicAdd(&accD[h][loc], den[h]);
        atomicAdd(&accN[h][loc], num[h]);
    }
    __syncthreads();
    // finalize one thread per node
    if (t < BKT_NODES) {
        int node = (b << BKT_SHIFT) + t;
        if (node < N) {
            row_start[node] = b * CAP + ob;
            row_deg[node] = deg;
            float xn = xloc[t];
            float acc = 0.f;
#pragma unroll
            for (int h = 0; h < NHEADS; ++h) {
                float e = xn * (sS1[h] + sD1[h]);      // self-loop
                e = e > 0.f ? e : NEG_SLOPE * e;
                float ex = __expf(e);
                float dsum = accD[h][t] + ex + EPSV;
                float nsum = accN[h][t] + ex * xn;
                float z = nsum / dsum;
#pragma unroll
                for (int c = 0; c < NCH; ++c) {
                    int k = h * NCH + c;
                    float vv = W1[k] * z + b1[k];
                    vv = vv > 0.f ? vv : (__expf(vv) - 1.f);   // elu
                    acc += vv * W2[k];
                }
            }
            h2out[node] = acc;
        }
    }
}

// Layer 2: 4 threads per node over sorted runs, shfl_xor combine.
__global__ __launch_bounds__(256) void gat_gather2_kernel(
        int N, const float* __restrict__ h2,
        const unsigned int* __restrict__ binned,
        const int* __restrict__ row_start, const int* __restrict__ row_deg,
        const float* __restrict__ as2p, const float* __restrict__ ad2p,
        const float* __restrict__ b2, float* __restrict__ out) {
    int g = blockIdx.x * blockDim.x + threadIdx.x;
    int n = g >> 2;
    int q = g & 3;
    bool valid = (n < N);
    int nc = valid ? n : (N - 1);
    float a_s = as2p[0], a_d = ad2p[0];
    float hn = h2[nc];
    float adc = hn * a_d;
    int st = row_start[nc];
    int dg = valid ? row_deg[nc] : 0;
    int lo = st + (dg * q) / 4;
    int hi = st + (dg * (q + 1)) / 4;
    float den = 0.f, num = 0.f;
    int j = lo;
    for (; j + 2 <= hi; j += 2) {
        unsigned int e0 = binned[j], e1 = binned[j + 1];
        float h0 = h2[e0], h1 = h2[e1];
        float ea = h0 * a_s + adc; ea = ea > 0.f ? ea : NEG_SLOPE * ea;
        float eb = h1 * a_s + adc; eb = eb > 0.f ? eb : NEG_SLOPE * eb;
        float fa = __expf(ea), fb = __expf(eb);
        den += fa + fb;
        num += fa * h0 + fb * h1;
    }
    if (j < hi) {
        unsigned int e0 = binned[j];
        float h0 = h2[e0];
        float ea = h0 * a_s + adc;
        ea = ea > 0.f ? ea : NEG_SLOPE * ea;
        float fa = __expf(ea);
        den += fa;
        num += fa * h0;
    }
    den += __shfl_xor(den, 1); den += __shfl_xor(den, 2);
    num += __shfl_xor(num, 1); num += __shfl_xor(num, 2);
    if (q == 0 && valid) {
        float e = hn * (a_s + a_d);                    // self-loop
        e = e > 0.f ? e : NEG_SLOPE * e;
        float ex = __expf(e);
        out[n] = (num + ex * hn) / (den + ex + EPSV) + b2[0];
    }
}

extern "C" void kernel_launch(void* const* d_in, const int* in_sizes, int n_in,
                              void* d_out, int out_size, void* d_ws, size_t ws_size,
                              hipStream_t stream) {
    const float* x   = (const float*)d_in[0];
    const int*   ei  = (const int*)d_in[1];
    const float* W1  = (const float*)d_in[2];
    const float* as1 = (const float*)d_in[3];
    const float* ad1 = (const float*)d_in[4];
    const float* b1  = (const float*)d_in[5];
    const float* W2  = (const float*)d_in[6];
    const float* as2 = (const float*)d_in[7];
    const float* ad2 = (const float*)d_in[8];
    const float* b2  = (const float*)d_in[9];
    float* out = (float*)d_out;

    int N = in_sizes[0];       // 100000
    int E = in_sizes[1] / 2;   // 1600000

    int nbuckets = (N + BKT_NODES - 1) >> BKT_SHIFT;   // 1563
    int nbin     = (E + BIN_EPB - 1) / BIN_EPB;        // 196
    int nb2      = (4 * N + 255) / 256;                // 1563

    // Workspace: h2[N]f | row_start[N]i | row_deg[N]i | bkt_cnt[nbuckets]i |
    // binned[nbuckets*CAP]u   (~14 MB of 268 MB ws)
    float* h2        = (float*)d_ws;
    int*   row_start = (int*)(h2 + N);
    int*   row_deg   = row_start + N;
    int*   bkt_cnt   = row_deg + N;
    unsigned int* binned = (unsigned int*)(bkt_cnt + nbuckets);

    hipMemsetAsync(bkt_cnt, 0, (size_t)nbuckets * sizeof(int), stream);

    gat_bin_kernel<<<nbin, 256, 0, stream>>>(ei, E, nbuckets, bkt_cnt, binned);
    gat_gather1_kernel<<<nbuckets, 256, 0, stream>>>(N, x, binned, bkt_cnt,
                                                     W1, as1, ad1, b1, W2,
                                                     h2, row_start, row_deg);
    gat_gather2_kernel<<<nb2, 256, 0, stream>>>(N, h2, binned, row_start, row_deg,
                                                as2, ad2, b2, out);
}

// Round 10
// 141.174 us; speedup vs baseline: 2.3485x; 1.1760x over previous
//
#include <hip/hip_runtime.h>

#define NEG_SLOPE 0.2f
#define EPSV 1e-16f
#define NHEADS 8
#define NCH 16
#define BKT_SHIFT 7        // 128 nodes per bucket
#define BKT_NODES 128
#define CAP 4096           // bucket capacity (mean 2048, ~45 sigma slack)
#define BIN_EPB 4096       // edges per block in bin pass (16/thread)
#define MAX_BKT 800

// Bin pass, block-aggregated: LDS bucket histogram gives local ranks; one
// global atomic per (block, nonempty bucket) reserves a contiguous range at
// fixed offset b*CAP; clustered writes of packed (src<<7 | dst&127).
// binned (12.8 MB) is L2-resident, so scattered small writes merge in L2.
__global__ __launch_bounds__(256) void gat_bin_kernel(
        const int* __restrict__ ei, int E, int nbuckets,
        int* __restrict__ bkt_cnt, unsigned int* __restrict__ binned) {
    __shared__ int hist[MAX_BKT];
    __shared__ int gbase[MAX_BKT];
    int t = threadIdx.x;
    for (int i = t; i < nbuckets; i += 256) hist[i] = 0;
    __syncthreads();
    int base = blockIdx.x * BIN_EPB;
    int lr[BIN_EPB / 256];   // 16 local ranks
#pragma unroll
    for (int k = 0; k < BIN_EPB / 1024; ++k) {
        int idx = base + k * 1024 + t * 4;
        if (idx + 3 < E) {
            int4 d4 = *(const int4*)(ei + E + idx);
            lr[4 * k + 0] = atomicAdd(&hist[d4.x >> BKT_SHIFT], 1);
            lr[4 * k + 1] = atomicAdd(&hist[d4.y >> BKT_SHIFT], 1);
            lr[4 * k + 2] = atomicAdd(&hist[d4.z >> BKT_SHIFT], 1);
            lr[4 * k + 3] = atomicAdd(&hist[d4.w >> BKT_SHIFT], 1);
        } else {
            for (int u = 0; u < 4; ++u)
                if (idx + u < E)
                    lr[4 * k + u] = atomicAdd(&hist[ei[E + idx + u] >> BKT_SHIFT], 1);
        }
    }
    __syncthreads();
    for (int i = t; i < nbuckets; i += 256) {
        int c = hist[i];
        gbase[i] = c ? (i * CAP + atomicAdd(&bkt_cnt[i], c)) : 0;
    }
    __syncthreads();
#pragma unroll
    for (int k = 0; k < BIN_EPB / 1024; ++k) {
        int idx = base + k * 1024 + t * 4;
        if (idx + 3 < E) {
            int4 s4 = *(const int4*)(ei + idx);
            int4 d4 = *(const int4*)(ei + E + idx);
            binned[gbase[d4.x >> BKT_SHIFT] + lr[4 * k + 0]] =
                ((unsigned int)s4.x << BKT_SHIFT) | (unsigned int)(d4.x & (BKT_NODES - 1));
            binned[gbase[d4.y >> BKT_SHIFT] + lr[4 * k + 1]] =
                ((unsigned int)s4.y << BKT_SHIFT) | (unsigned int)(d4.y & (BKT_NODES - 1));
            binned[gbase[d4.z >> BKT_SHIFT] + lr[4 * k + 2]] =
                ((unsigned int)s4.z << BKT_SHIFT) | (unsigned int)(d4.z & (BKT_NODES - 1));
            binned[gbase[d4.w >> BKT_SHIFT] + lr[4 * k + 3]] =
                ((unsigned int)s4.w << BKT_SHIFT) | (unsigned int)(d4.w & (BKT_NODES - 1));
        } else {
            for (int u = 0; u < 4; ++u)
                if (idx + u < E) {
                    unsigned int s = (unsigned int)ei[idx + u];
                    int d = ei[E + idx + u];
                    binned[gbase[d >> BKT_SHIFT] + lr[4 * k + u]] =
                        (s << BKT_SHIFT) | (unsigned int)(d & (BKT_NODES - 1));
                }
        }
    }
}

// Layer 1: one block per 128-node bucket, 256 threads = 2 per node (ADJACENT
// lanes -> shfl combine, no atomics). LDS counting sort, per-node register
// gather split in half, shfl_xor(1) combine. Writes sorted srcs + row meta
// + h2.
__global__ __launch_bounds__(256) void gat_gather1_kernel(
        int N, const float* __restrict__ x,
        unsigned int* __restrict__ binned, const int* __restrict__ bkt_cnt,
        const float* __restrict__ W1, const float* __restrict__ as1,
        const float* __restrict__ ad1, const float* __restrict__ b1,
        const float* __restrict__ W2, float* __restrict__ h2out,
        int* __restrict__ row_start, int* __restrict__ row_deg) {
    __shared__ unsigned int ed[CAP];          // 16 KB sorted srcs
    __shared__ int cnt[BKT_NODES], offs[BKT_NODES], cur[BKT_NODES];
    __shared__ float xloc[BKT_NODES];
    __shared__ float sS1[NHEADS], sD1[NHEADS];
    int b = blockIdx.x, t = threadIdx.x;
    if (t < NHEADS) {
        float s = 0.f, d = 0.f;
        for (int c = 0; c < NCH; ++c) {
            float w = W1[t * NCH + c];
            s += w * as1[t * NCH + c];
            d += w * ad1[t * NCH + c];
        }
        sS1[t] = s; sD1[t] = d;
    }
    if (t < BKT_NODES) {
        int node = (b << BKT_SHIFT) + t;
        xloc[t] = (node < N) ? x[node] : 0.f;
        cnt[t] = 0;
    }
    __syncthreads();
    int nE = bkt_cnt[b]; if (nE > CAP) nE = CAP;
    const unsigned int* bb = binned + (size_t)b * CAP;
    // count local dsts
    for (int j0 = 0; j0 < nE; j0 += 1024) {
        int idx = j0 + t * 4;
        if (idx + 3 < nE) {
            uint4 qv = *(const uint4*)(bb + idx);
            atomicAdd(&cnt[qv.x & (BKT_NODES - 1)], 1);
            atomicAdd(&cnt[qv.y & (BKT_NODES - 1)], 1);
            atomicAdd(&cnt[qv.z & (BKT_NODES - 1)], 1);
            atomicAdd(&cnt[qv.w & (BKT_NODES - 1)], 1);
        } else {
            for (int u = 0; u < 4; ++u)
                if (idx + u < nE) atomicAdd(&cnt[bb[idx + u] & (BKT_NODES - 1)], 1);
        }
    }
    __syncthreads();
    // 128-wide Hillis-Steele inclusive scan
    if (t < BKT_NODES) offs[t] = cnt[t];
    __syncthreads();
    for (int o = 1; o < BKT_NODES; o <<= 1) {
        int v = (t < BKT_NODES && t >= o) ? offs[t - o] : 0;
        __syncthreads();
        if (t < BKT_NODES) offs[t] += v;
        __syncthreads();
    }
    if (t < BKT_NODES) cur[t] = offs[t] - cnt[t];
    __syncthreads();
    // scatter srcs into sorted LDS positions
    for (int j0 = 0; j0 < nE; j0 += 1024) {
        int idx = j0 + t * 4;
        if (idx + 3 < nE) {
            uint4 qv = *(const uint4*)(bb + idx);
            ed[atomicAdd(&cur[qv.x & (BKT_NODES - 1)], 1)] = qv.x >> BKT_SHIFT;
            ed[atomicAdd(&cur[qv.y & (BKT_NODES - 1)], 1)] = qv.y >> BKT_SHIFT;
            ed[atomicAdd(&cur[qv.z & (BKT_NODES - 1)], 1)] = qv.z >> BKT_SHIFT;
            ed[atomicAdd(&cur[qv.w & (BKT_NODES - 1)], 1)] = qv.w >> BKT_SHIFT;
        } else {
            for (int u = 0; u < 4; ++u)
                if (idx + u < nE) {
                    unsigned int v = bb[idx + u];
                    ed[atomicAdd(&cur[v & (BKT_NODES - 1)], 1)] = v >> BKT_SHIFT;
                }
        }
    }
    __syncthreads();
    // write back sorted srcs for layer 2 (coalesced, L2-resident)
    for (int j0 = 0; j0 < nE; j0 += 1024) {
        int idx = j0 + t * 4;
        if (idx + 3 < nE) {
            *(uint4*)(binned + (size_t)b * CAP + idx) = *(const uint4*)(ed + idx);
        } else {
            for (int u = 0; u < 4; ++u)
                if (idx + u < nE) binned[(size_t)b * CAP + idx + u] = ed[idx + u];
        }
    }
    // per-node gather, 2 adjacent-lane threads per node
    int loc = t >> 1;
    int q = t & 1;
    int deg = cnt[loc];
    int ob = offs[loc] - deg;
    int lo = ob + ((deg * q) >> 1);
    int hi = ob + ((deg * (q + 1)) >> 1);
    float xd = xloc[loc];
    float S1[NHEADS], A[NHEADS], den[NHEADS], num[NHEADS];
#pragma unroll
    for (int h = 0; h < NHEADS; ++h) {
        S1[h] = sS1[h];
        A[h] = xd * sD1[h];
        den[h] = 0.f;
        num[h] = 0.f;
    }
    int j = lo;
    for (; j + 2 <= hi; j += 2) {
        unsigned int e0 = ed[j], e1 = ed[j + 1];
        float x0 = x[e0], x1 = x[e1];
#pragma unroll
        for (int h = 0; h < NHEADS; ++h) {
            float ea = x0 * S1[h] + A[h]; ea = ea > 0.f ? ea : NEG_SLOPE * ea;
            float eb = x1 * S1[h] + A[h]; eb = eb > 0.f ? eb : NEG_SLOPE * eb;
            float fa = __expf(ea), fb = __expf(eb);
            den[h] += fa + fb;
            num[h] += fa * x0 + fb * x1;
        }
    }
    if (j < hi) {
        unsigned int e0 = ed[j];
        float x0 = x[e0];
#pragma unroll
        for (int h = 0; h < NHEADS; ++h) {
            float ea = x0 * S1[h] + A[h];
            ea = ea > 0.f ? ea : NEG_SLOPE * ea;
            float fa = __expf(ea);
            den[h] += fa;
            num[h] += fa * x0;
        }
    }
    // same-wave combine of the two halves
#pragma unroll
    for (int h = 0; h < NHEADS; ++h) {
        den[h] += __shfl_xor(den[h], 1);
        num[h] += __shfl_xor(num[h], 1);
    }
    if (q == 0) {
        int node = (b << BKT_SHIFT) + loc;
        if (node < N) {
            row_start[node] = b * CAP + ob;
            row_deg[node] = deg;
            float xn = xd;
            float acc = 0.f;
#pragma unroll
            for (int h = 0; h < NHEADS; ++h) {
                float e = xn * (S1[h] + sD1[h]);       // self-loop
                e = e > 0.f ? e : NEG_SLOPE * e;
                float ex = __expf(e);
                float dsum = den[h] + ex + EPSV;
                float nsum = num[h] + ex * xn;
                float z = nsum / dsum;
#pragma unroll
                for (int c = 0; c < NCH; ++c) {
                    int k = h * NCH + c;
                    float vv = W1[k] * z + b1[k];
                    vv = vv > 0.f ? vv : (__expf(vv) - 1.f);   // elu
                    acc += vv * W2[k];
                }
            }
            h2out[node] = acc;
        }
    }
}

// Layer 2: 2 adjacent-lane threads per node over sorted runs, shfl combine.
__global__ __launch_bounds__(256) void gat_gather2_kernel(
        int N, const float* __restrict__ h2,
        const unsigned int* __restrict__ binned,
        const int* __restrict__ row_start, const int* __restrict__ row_deg,
        const float* __restrict__ as2p, const float* __restrict__ ad2p,
        const float* __restrict__ b2, float* __restrict__ out) {
    int g = blockIdx.x * blockDim.x + threadIdx.x;
    int n = g >> 1;
    int q = g & 1;
    bool valid = (n < N);
    int nc = valid ? n : 0;
    float a_s = as2p[0], a_d = ad2p[0];
    float hn = h2[nc];
    float adc = hn * a_d;
    int st = row_start[nc];
    int dg = valid ? row_deg[nc] : 0;
    int lo = st + ((dg * q) >> 1);
    int hi = st + ((dg * (q + 1)) >> 1);
    float den = 0.f, num = 0.f;
    int j = lo;
    for (; j + 2 <= hi; j += 2) {
        unsigned int e0 = binned[j], e1 = binned[j + 1];
        float h0 = h2[e0], h1 = h2[e1];
        float ea = h0 * a_s + adc; ea = ea > 0.f ? ea : NEG_SLOPE * ea;
        float eb = h1 * a_s + adc; eb = eb > 0.f ? eb : NEG_SLOPE * eb;
        float fa = __expf(ea), fb = __expf(eb);
        den += fa + fb;
        num += fa * h0 + fb * h1;
    }
    if (j < hi) {
        unsigned int e0 = binned[j];
        float h0 = h2[e0];
        float ea = h0 * a_s + adc;
        ea = ea > 0.f ? ea : NEG_SLOPE * ea;
        float fa = __expf(ea);
        den += fa;
        num += fa * h0;
    }
    den += __shfl_xor(den, 1);
    num += __shfl_xor(num, 1);
    if (q == 0 && valid) {
        float e = hn * (a_s + a_d);                    // self-loop
        e = e > 0.f ? e : NEG_SLOPE * e;
        float ex = __expf(e);
        out[n] = (num + ex * hn) / (den + ex + EPSV) + b2[0];
    }
}

extern "C" void kernel_launch(void* const* d_in, const int* in_sizes, int n_in,
                              void* d_out, int out_size, void* d_ws, size_t ws_size,
                              hipStream_t stream) {
    const float* x   = (const float*)d_in[0];
    const int*   ei  = (const int*)d_in[1];
    const float* W1  = (const float*)d_in[2];
    const float* as1 = (const float*)d_in[3];
    const float* ad1 = (const float*)d_in[4];
    const float* b1  = (const float*)d_in[5];
    const float* W2  = (const float*)d_in[6];
    const float* as2 = (const float*)d_in[7];
    const float* ad2 = (const float*)d_in[8];
    const float* b2  = (const float*)d_in[9];
    float* out = (float*)d_out;

    int N = in_sizes[0];       // 100000
    int E = in_sizes[1] / 2;   // 1600000

    int nbuckets = (N + BKT_NODES - 1) >> BKT_SHIFT;   // 782
    int nbin     = (E + BIN_EPB - 1) / BIN_EPB;        // 391
    int nb2      = (2 * N + 255) / 256;                // 782

    // Workspace: h2[N]f | row_start[N]i | row_deg[N]i | bkt_cnt[nbuckets]i |
    // (pad to 16B) | binned[nbuckets*CAP]u   (~14 MB of 268 MB ws)
    float* h2        = (float*)d_ws;
    int*   row_start = (int*)(h2 + N);
    int*   row_deg   = row_start + N;
    int*   bkt_cnt   = row_deg + N;
    size_t ofs = ((size_t)3 * N + nbuckets + 3) & ~(size_t)3;  // 16B align
    unsigned int* binned = (unsigned int*)d_ws + ofs;

    hipMemsetAsync(bkt_cnt, 0, (size_t)nbuckets * sizeof(int), stream);

    gat_bin_kernel<<<nbin, 256, 0, stream>>>(ei, E, nbuckets, bkt_cnt, binned);
    gat_gather1_kernel<<<nbuckets, 256, 0, stream>>>(N, x, binned, bkt_cnt,
                                                     W1, as1, ad1, b1, W2,
                                                     h2, row_start, row_deg);
    gat_gather2_kernel<<<nb2, 256, 0, stream>>>(N, h2, binned, row_start, row_deg,
                                                as2, ad2, b2, out);
}